// Round 2
// baseline (51.329 us; speedup 1.0000x reference)
//
#include <hip/hip_runtime.h>

#define NF 39
#define NE 40
#define NP 741
#define NB 4096
#define NSLOT 1536      // 6 tiles * 256 raw accumulator slots per sample
#define SPB 4           // samples per block in k1 (one per wave)
#define LDS_STRIDE 72   // bf16 elems per padded row (144 B -> bank-spread fragment reads)
#define K2_BLOCKS 256
#define ROWS_PER_K2 16  // 4096 / 256

typedef __attribute__((ext_vector_type(8))) short short8;
typedef __attribute__((ext_vector_type(4))) float floatx4;

__device__ __forceinline__ unsigned short f2bf(float f) {
    unsigned int b = __float_as_uint(f);
    b += 0x7FFFu + ((b >> 16) & 1u);   // round-to-nearest-even
    return (unsigned short)(b >> 16);
}

// ---------------- Kernel 1: gather -> bf16 LDS -> MFMA Gram tiles ----------------
__global__ __launch_bounds__(256) void fm_k1(
    const int* __restrict__ inputs, const float* __restrict__ w,
    const float* __restrict__ v, float* __restrict__ raw, float* __restrict__ lsum)
{
    __shared__ unsigned short xv[SPB][48 * LDS_STRIDE];  // 27648 B, zero-padded
    __shared__ int idxs[SPB][NF];
    const int t = threadIdx.x;
    const int b0 = blockIdx.x * SPB;

    // zero LDS (covers pad rows 39..47 and pad cols 40..63)
    unsigned int* lz = (unsigned int*)&xv[0][0];
    for (int q = t; q < SPB * 48 * LDS_STRIDE / 2; q += 256) lz[q] = 0u;
    if (t < SPB * NF) idxs[t / NF][t % NF] = inputs[b0 * NF + t];
    __syncthreads();

    // gather 4 samples x 39 rows x 10 float4, convert to bf16, stage to LDS
    for (int q = t; q < SPB * NF * (NE / 4); q += 256) {
        const int s    = q / (NF * (NE / 4));
        const int rsub = q - s * (NF * (NE / 4));
        const int r    = rsub / (NE / 4);
        const int e4   = rsub - r * (NE / 4);
        const float4 val = *reinterpret_cast<const float4*>(
            v + (size_t)idxs[s][r] * NE + e4 * 4);
        uint2 pk;
        pk.x = (unsigned int)f2bf(val.x) | ((unsigned int)f2bf(val.y) << 16);
        pk.y = (unsigned int)f2bf(val.z) | ((unsigned int)f2bf(val.w) << 16);
        *reinterpret_cast<uint2*>(&xv[s][r * LDS_STRIDE + e4 * 4]) = pk;
    }

    // first-order term: one wave per sample
    const int wid = t >> 6, lane = t & 63;
    float wv = (lane < NF) ? w[idxs[wid][lane]] : 0.0f;
#pragma unroll
    for (int o = 32; o > 0; o >>= 1) wv += __shfl_down(wv, o, 64);
    if (lane == 0) lsum[b0 + wid] = wv;
    __syncthreads();

    // load fragments F[kchunk][I]; same frag used as A and B => Gram tile
    short8 F[2][3];
    const unsigned short* base = &xv[wid][0];
#pragma unroll
    for (int c = 0; c < 2; ++c)
#pragma unroll
        for (int I = 0; I < 3; ++I) {
            const int row  = (lane & 15) + 16 * I;
            const int eoff = (lane >> 4) * 8 + 32 * c;
            F[c][I] = *reinterpret_cast<const short8*>(base + row * LDS_STRIDE + eoff);
        }

    floatx4 acc[6] = {};
    // tiles: (0,0),(0,1),(0,2),(1,1),(1,2),(2,2)
#pragma unroll
    for (int c = 0; c < 2; ++c) {
        acc[0] = __builtin_amdgcn_mfma_f32_16x16x32_bf16(F[c][0], F[c][0], acc[0], 0, 0, 0);
        acc[1] = __builtin_amdgcn_mfma_f32_16x16x32_bf16(F[c][0], F[c][1], acc[1], 0, 0, 0);
        acc[2] = __builtin_amdgcn_mfma_f32_16x16x32_bf16(F[c][0], F[c][2], acc[2], 0, 0, 0);
        acc[3] = __builtin_amdgcn_mfma_f32_16x16x32_bf16(F[c][1], F[c][1], acc[3], 0, 0, 0);
        acc[4] = __builtin_amdgcn_mfma_f32_16x16x32_bf16(F[c][1], F[c][2], acc[4], 0, 0, 0);
        acc[5] = __builtin_amdgcn_mfma_f32_16x16x32_bf16(F[c][2], F[c][2], acc[5], 0, 0, 0);
    }

    // coalesced raw-slot store: slot = tile*256 + lane*4 + reg
    float* orow = raw + (size_t)(b0 + wid) * NSLOT;
#pragma unroll
    for (int tl = 0; tl < 6; ++tl)
        *reinterpret_cast<floatx4*>(orow + tl * 256 + lane * 4) = acc[tl];
}

// ---------------- Kernel 2a: coalesced partial column stats ----------------
__global__ __launch_bounds__(256) void fm_k2a(
    const float* __restrict__ raw, float* __restrict__ partial)
{
    const int t = threadIdx.x;
    const int r0 = blockIdx.x * ROWS_PER_K2;
    float sum[6] = {}, sq[6] = {};
    for (int r = 0; r < ROWS_PER_K2; ++r) {
        const float* row = raw + (size_t)(r0 + r) * NSLOT;
#pragma unroll
        for (int c = 0; c < 6; ++c) {
            const float x = row[t + 256 * c];
            sum[c] += x;
            sq[c] = fmaf(x, x, sq[c]);
        }
    }
    float* p = partial + (size_t)blockIdx.x * 2 * NSLOT;
#pragma unroll
    for (int c = 0; c < 6; ++c) {
        p[t + 256 * c] = sum[c];
        p[NSLOT + t + 256 * c] = sq[c];
    }
}

// ---------------- Kernel 2b: finalize mean/scale per slot ----------------
__global__ __launch_bounds__(64) void fm_k2b(
    const float* __restrict__ partial, const float* __restrict__ ew,
    float* __restrict__ meanArr, float* __restrict__ scaleArr)
{
    const int slot = blockIdx.x * 64 + threadIdx.x;   // 24 blocks x 64
    float sum = 0.f, sq = 0.f;
    for (int i = 0; i < K2_BLOCKS; ++i) {
        const float* p = partial + (size_t)i * 2 * NSLOT;
        sum += p[slot];
        sq  += p[NSLOT + slot];
    }
    const float m   = sum * (1.0f / NB);
    const float var = sq  * (1.0f / NB) - m * m;
    // slot -> (gi, gj) -> pair index
    const int tile = slot >> 8;
    const int l    = (slot & 255) >> 2;
    const int q    = slot & 3;
    const int TI[6] = {0, 0, 0, 1, 1, 2};
    const int TJ[6] = {0, 1, 2, 1, 2, 2};
    const int gi = 16 * TI[tile] + ((l >> 4) << 2) + q;
    const int gj = 16 * TJ[tile] + (l & 15);
    float scl = 0.0f;
    if (gi < gj && gj < NF) {
        const int p = 38 * gi - (gi * (gi - 1)) / 2 + (gj - gi - 1);
        scl = ew[p] * rsqrtf(var + 1.0e-3f);
    }
    meanArr[slot]  = m;
    scaleArr[slot] = scl;
}

// ---------------- Kernel 3: normalize + reduce + first-order ----------------
__global__ __launch_bounds__(256) void fm_k3(
    const float* __restrict__ raw, const float* __restrict__ lsum,
    const float* __restrict__ meanArr, const float* __restrict__ scaleArr,
    const float* __restrict__ bias, float* __restrict__ out)
{
    const int b = blockIdx.x;
    const int t = threadIdx.x;
    const float* row = raw + (size_t)b * NSLOT;
    float acc = 0.0f;
#pragma unroll
    for (int c = 0; c < 6; ++c) {
        const int slot = t + 256 * c;
        acc += (row[slot] - meanArr[slot]) * scaleArr[slot];
    }
    __shared__ float s1[4];
#pragma unroll
    for (int o = 32; o > 0; o >>= 1) acc += __shfl_down(acc, o, 64);
    if ((t & 63) == 0) s1[t >> 6] = acc;
    __syncthreads();
    if (t == 0) out[b] = lsum[b] + (s1[0] + s1[1] + s1[2] + s1[3]) + bias[0];
}

extern "C" void kernel_launch(void* const* d_in, const int* in_sizes, int n_in,
                              void* d_out, int out_size, void* d_ws, size_t ws_size,
                              hipStream_t stream)
{
    const int*   inputs = (const int*)  d_in[0];
    // d_in[1] = rows, d_in[2] = cols: combinatorial order is reproduced in-kernel
    const float* w      = (const float*)d_in[3];
    const float* v      = (const float*)d_in[4];
    const float* bias   = (const float*)d_in[5];
    const float* ew     = (const float*)d_in[6];
    float*       out    = (float*)      d_out;

    // ws layout (floats): raw[NB*NSLOT] | partial[256*2*NSLOT] | mean[NSLOT] | scale[NSLOT] | lsum[NB]
    float* raw     = (float*)d_ws;
    float* partial = raw + (size_t)NB * NSLOT;
    float* meanA   = partial + (size_t)K2_BLOCKS * 2 * NSLOT;
    float* scaleA  = meanA + NSLOT;
    float* lsum    = scaleA + NSLOT;

    fm_k1 <<<NB / SPB,   256, 0, stream>>>(inputs, w, v, raw, lsum);
    fm_k2a<<<K2_BLOCKS,  256, 0, stream>>>(raw, partial);
    fm_k2b<<<NSLOT / 64,  64, 0, stream>>>(partial, ew, meanA, scaleA);
    fm_k3 <<<NB,         256, 0, stream>>>(raw, lsum, meanA, scaleA, bias, out);
}